// Round 13
// baseline (136.627 us; speedup 1.0000x reference)
//
#include <hip/hip_runtime.h>
#include <hip/hip_bf16.h>
#include <math.h>

// Problem constants
#define BB 4
#define LL 2048
#define HH 8
#define DD 64          // head dim
#define MM 256         // nb_features
#define DIMM 512
#define TT 64          // chunk length
#define NCHUNK (LL/TT) // 32

constexpr float K_SCALE = 0.35355339059327379f; // 64^-0.25
constexpr float K_RATIO = 0.0625f;              // 256^-0.5
constexpr float K_EPS   = 1e-6f;

using short8 = __attribute__((ext_vector_type(8))) short;
using f32x4  = __attribute__((ext_vector_type(4))) float;
typedef _Float16 f16_t;

__device__ inline unsigned short f2b_u16(float x) {
    __hip_bfloat16 h = __float2bfloat16(x);
    return *reinterpret_cast<unsigned short*>(&h);
}
__device__ inline ushort4 f2b4(float4 v) {
    ushort4 o; o.x = f2b_u16(v.x); o.y = f2b_u16(v.y); o.z = f2b_u16(v.z); o.w = f2b_u16(v.w);
    return o;
}
__device__ inline unsigned short f2h_u16(float x) {
    f16_t h = (f16_t)x;
    return *reinterpret_cast<unsigned short*>(&h);
}
__device__ inline float h2f(unsigned short u) {
    f16_t h = *reinterpret_cast<f16_t*>(&u);
    return (float)h;
}
__device__ inline float b2f_u16(unsigned short u) {
    __hip_bfloat16 h = *reinterpret_cast<__hip_bfloat16*>(&u);
    return __bfloat162float(h);
}

// XOR-swizzled byte offset into the chunk_state kT tile ([m][t] bf16, row
// stride 72 elems = 144B).
#define KSWZ(m, te) ((((m)*144) + ((te)*2)) ^ ((((m)>>3) & 3) << 4))

// XOR-swizzled byte offset into the Pl proj tile ([m][k] bf16, linear 64-elem
// rows = 128B). Bits 4-6 XOR'd by (m>>1)&7.
#define PSWZ(m, ke) ((((m)*128) + ((ke)*2)) ^ ((((m)>>1) & 7) << 4))

// XCD-grouping remap for (8 ct, 64 rt) grids (verified rounds 8/12).
__device__ inline void xcd_remap(int* ct, int* rt) {
    const int fid = blockIdx.x + 8*blockIdx.y;   // 0..511
    const int xcd = fid & 7;
    *rt = xcd*8 + (fid >> 6);                    // 0..63
    *ct = (fid >> 3) & 7;                        // 0..7
}

// ---------------------------------------------------------------------------
// Merged f32 -> bf16 casts: q/k/v inputs + 4 weights. One dispatch.
// ---------------------------------------------------------------------------
__global__ __launch_bounds__(256)
void cast_all_kernel(const float* __restrict__ q, const float* __restrict__ k,
                     const float* __restrict__ v,
                     const float* __restrict__ w0, const float* __restrict__ w1,
                     const float* __restrict__ w2, const float* __restrict__ w3,
                     __hip_bfloat16* __restrict__ qo, __hip_bfloat16* __restrict__ ko,
                     __hip_bfloat16* __restrict__ vo,
                     __hip_bfloat16* __restrict__ o0, __hip_bfloat16* __restrict__ o1,
                     __hip_bfloat16* __restrict__ o2, __hip_bfloat16* __restrict__ o3)
{
    const int NIN = 1 << 20;    // float4 per input tensor
    const int NW  = 1 << 16;    // float4 per weight
    const int total = 3*NIN + 4*NW;
    for (int i = blockIdx.x*256 + threadIdx.x; i < total; i += gridDim.x*256) {
        const float* src;
        __hip_bfloat16* dst;
        int j;
        if (i < 3*NIN) {
            const int t = i / NIN; j = i - t*NIN;
            src = (t == 0) ? q : (t == 1) ? k : v;
            dst = (t == 0) ? qo : (t == 1) ? ko : vo;
        } else {
            const int r = i - 3*NIN;
            const int t = r / NW; j = r - t*NW;
            src = (t == 0) ? w0 : (t == 1) ? w1 : (t == 2) ? w2 : w3;
            dst = (t == 0) ? o0 : (t == 1) ? o1 : (t == 2) ? o2 : o3;
        }
        float4 x = reinterpret_cast<const float4*>(src)[j];
        reinterpret_cast<ushort4*>(dst)[j] = f2b4(x);
    }
}

// ---------------------------------------------------------------------------
// FUSED qkv projection + feature maps + V transpose (verified rounds 11/12),
// now with LDS-staged COALESCED epilogue stores (256B row segments).
// Grid (8 ct, 64 rt, 3 z), 256 threads = 4 waves.
// ---------------------------------------------------------------------------
__global__ __launch_bounds__(256, 3)
void qkv_feat_kernel(const __hip_bfloat16* __restrict__ Xq, const __hip_bfloat16* __restrict__ Xk,
                     const __hip_bfloat16* __restrict__ Xv,
                     const __hip_bfloat16* __restrict__ Wq, const float* __restrict__ bq,
                     const __hip_bfloat16* __restrict__ Wk, const float* __restrict__ bk,
                     const __hip_bfloat16* __restrict__ Wv, const float* __restrict__ bv,
                     const float* __restrict__ P,
                     __hip_bfloat16* __restrict__ qp_b, unsigned short* __restrict__ ddT,
                     float* __restrict__ part, __hip_bfloat16* __restrict__ vT_b)
{
    constexpr int LDT = 72;
    constexpr int LDS2 = 136;               // stage row pitch (272B = 17x16B)
    __shared__ __hip_bfloat16 smem[25600];  // 51.2KB: phase1 As|Bs; phase2 T|Pl; epi stage
    __shared__ float diagl[128];
    __shared__ float wmx[4];
    __hip_bfloat16* As = smem;              // 128*72
    __hip_bfloat16* Bs = smem + 9216;       // 64*72
    __hip_bfloat16* T  = smem;              // aliases As after barrier
    char* pbuf = (char*)(smem + 9216);      // Pl 256x64 PSWZ (32768B)
    unsigned short* stage = (unsigned short*)smem;  // epilogue stage 128*136*2 = 34816B

    const int z = blockIdx.z;
    const __hip_bfloat16* X = (z == 0) ? Xq : (z == 1) ? Xk : Xv;
    const __hip_bfloat16* W = (z == 0) ? Wq : (z == 1) ? Wk : Wv;
    const float* bias = (z == 0) ? bq : (z == 1) ? bk : bv;
    const float postscale = (z == 2) ? 1.0f : K_SCALE;

    int ct, rt;
    xcd_remap(&ct, &rt);
    const int row0 = rt*128, col0 = ct*64;
    const int tid = threadIdx.x;
    const int lane = tid & 63;
    const int w = tid >> 6;
    const int wm = w * 32;
    const int l15 = lane & 15, l4 = lane >> 4;

    // ---- phase 1: projection (verified R10/R11) ----
    f32x4 acc[2][4];
#pragma unroll
    for (int mt = 0; mt < 2; ++mt)
#pragma unroll
        for (int nt = 0; nt < 4; ++nt) {
            f32x4 zf = {0.f, 0.f, 0.f, 0.f};
            acc[mt][nt] = zf;
        }

    for (int k0 = 0; k0 < DIMM; k0 += 64) {
#pragma unroll
        for (int i = 0; i < 4; ++i) {
            int lin = i*256 + tid;
            int r = lin >> 3, kc = (lin & 7)*8;
            *(uint4*)&As[r*LDT + kc] = *(const uint4*)(X + (size_t)(row0 + r)*DIMM + k0 + kc);
        }
#pragma unroll
        for (int i = 0; i < 2; ++i) {
            int lin = i*256 + tid;
            int r = lin >> 3, kc = (lin & 7)*8;
            *(uint4*)&Bs[r*LDT + kc] = *(const uint4*)(W + (size_t)(col0 + r)*DIMM + k0 + kc);
        }
        __syncthreads();
#pragma unroll
        for (int ks = 0; ks < 2; ++ks) {
            const int koff = ks*32 + l4*8;
            short8 aF[2], bF[4];
#pragma unroll
            for (int mt = 0; mt < 2; ++mt)
                aF[mt] = *(const short8*)&As[(wm + mt*16 + l15)*LDT + koff];
#pragma unroll
            for (int nt = 0; nt < 4; ++nt)
                bF[nt] = *(const short8*)&Bs[(nt*16 + l15)*LDT + koff];
#pragma unroll
            for (int mt = 0; mt < 2; ++mt)
#pragma unroll
                for (int nt = 0; nt < 4; ++nt)
                    acc[mt][nt] = __builtin_amdgcn_mfma_f32_16x16x32_bf16(aF[mt], bF[nt], acc[mt][nt], 0, 0, 0);
        }
        __syncthreads();
    }

    // ---- phase 2: tile -> T (bias+scale, bf16) ----
#pragma unroll
    for (int mt = 0; mt < 2; ++mt)
#pragma unroll
        for (int nt = 0; nt < 4; ++nt) {
            const float bval = bias[col0 + nt*16 + l15];
#pragma unroll
            for (int j = 0; j < 4; ++j) {
                const int r = wm + mt*16 + l4*4 + j;
                T[r*LDT + nt*16 + l15] = __float2bfloat16((acc[mt][nt][j] + bval) * postscale);
            }
        }
    if (z != 2) {
#pragma unroll
        for (int i = 0; i < 16; ++i) {
            int lin = i*256 + tid;
            int r = lin >> 4, kc = (lin & 15)*4;
            float4 v = *(const float4*)(P + (size_t)r*64 + kc);
            ushort4 o = f2b4(v);
            *(ushort4*)(pbuf + PSWZ(r, kc)) = o;
        }
    }
    __syncthreads();

    if (z == 2) {
        // vT via LDS transpose
        const int d = tid >> 2, q = tid & 3;
        const int b = row0 >> 11, l0loc = row0 & 2047;
        __hip_bfloat16* dst = vT_b + (((size_t)b*HH + ct)*DD + d)*LL + l0loc + q*32;
#pragma unroll
        for (int g = 0; g < 8; ++g) {
            ushort4 o;
            o.x = *(unsigned short*)&T[(q*32 + g*4 + 0)*LDT + d];
            o.y = *(unsigned short*)&T[(q*32 + g*4 + 1)*LDT + d];
            o.z = *(unsigned short*)&T[(q*32 + g*4 + 2)*LDT + d];
            o.w = *(unsigned short*)&T[(q*32 + g*4 + 3)*LDT + d];
            *(ushort4*)(dst + g*4) = o;
        }
        return;
    }

    // diag partials (reads T)
    {
        const int r = tid >> 1, half = tid & 1;
        float s = 0.f;
#pragma unroll
        for (int i = 0; i < 32; ++i) {
            float x = __bfloat162float(T[r*LDT + half*32 + i]);
            s += x*x;
        }
        s += __shfl_xor(s, 1);
        if (half == 0) diagl[r] = 0.5f * s;
    }

    // feature MFMA: dd[128 l x 256 m], K=64. acc2[mt 2][nt2 16].
    f32x4 acc2[2][16];
#pragma unroll
    for (int mt = 0; mt < 2; ++mt)
#pragma unroll
        for (int nt2 = 0; nt2 < 16; ++nt2) {
            f32x4 zf = {0.f,0.f,0.f,0.f};
            acc2[mt][nt2] = zf;
        }
#pragma unroll
    for (int ks = 0; ks < 2; ++ks) {
        const int ko = ks*32 + l4*8;
        short8 aF[2];
#pragma unroll
        for (int mt = 0; mt < 2; ++mt)
            aF[mt] = *(const short8*)&T[(wm + mt*16 + l15)*LDT + ko];
#pragma unroll
        for (int nt2 = 0; nt2 < 16; ++nt2) {
            short8 bF = *(const short8*)(pbuf + PSWZ(nt2*16 + l15, ko));
#pragma unroll
            for (int mt = 0; mt < 2; ++mt)
                acc2[mt][nt2] = __builtin_amdgcn_mfma_f32_16x16x32_bf16(aF[mt], bF, acc2[mt][nt2], 0, 0, 0);
        }
    }

    if (z == 1) {
        float mx = -3.0e38f;
#pragma unroll
        for (int mt = 0; mt < 2; ++mt)
#pragma unroll
            for (int nt2 = 0; nt2 < 16; ++nt2)
#pragma unroll
                for (int j = 0; j < 4; ++j)
                    mx = fmaxf(mx, acc2[mt][nt2][j]);
#pragma unroll
        for (int off = 32; off > 0; off >>= 1) mx = fmaxf(mx, __shfl_xor(mx, off));
        if (lane == 0) wmx[w] = mx;
    }
    __syncthreads();   // diagl (and wmx) ready; T/Pl now dead -> stage reuse OK

    const int b = row0 >> 11, l0loc = row0 & 2047;

    if (z == 0) {
        // cc per (mt,j) hoisted (rowmax over all 16 nt2 + cross-lane)
        float ccv[2][4];
#pragma unroll
        for (int mt = 0; mt < 2; ++mt)
#pragma unroll
            for (int j = 0; j < 4; ++j) {
                float m = acc2[mt][0][j];
#pragma unroll
                for (int nt2 = 1; nt2 < 16; ++nt2) m = fmaxf(m, acc2[mt][nt2][j]);
                m = fmaxf(m, __shfl_xor(m, 1));
                m = fmaxf(m, __shfl_xor(m, 2));
                m = fmaxf(m, __shfl_xor(m, 4));
                m = fmaxf(m, __shfl_xor(m, 8));
                ccv[mt][j] = diagl[wm + mt*16 + l4*4 + j] + m;
            }
        const size_t gb = ((size_t)b*HH + ct)*LL + l0loc;
#pragma unroll
        for (int half = 0; half < 2; ++half) {
            if (half) __syncthreads();   // protect stage against prior copy reads
#pragma unroll
            for (int mt = 0; mt < 2; ++mt)
#pragma unroll
                for (int j = 0; j < 4; ++j) {
                    const int r = wm + mt*16 + l4*4 + j;
                    const float cc = ccv[mt][j];
#pragma unroll
                    for (int q2 = 0; q2 < 8; ++q2) {
                        const int nt2 = half*8 + q2;
                        stage[r*LDS2 + q2*16 + l15] =
                            f2b_u16(K_RATIO * (__expf(acc2[mt][nt2][j] - cc) + K_EPS));
                    }
                }
            __syncthreads();
            // coalesced copy-out: 128 rows x 256B (16 uint4/row)
#pragma unroll
            for (int i = 0; i < 8; ++i) {
                int lin = i*256 + tid;
                int r = lin >> 4, seg = lin & 15;
                *(uint4*)(qp_b + (gb + r)*MM + half*128 + seg*8) =
                    *(uint4*)&stage[r*LDS2 + seg*8];
            }
        }
    } else {
        if (tid == 0)
            part[rt*8 + ct] = fmaxf(fmaxf(wmx[0], wmx[1]), fmaxf(wmx[2], wmx[3]));
        const size_t mb = ((size_t)b*HH + ct)*MM;
#pragma unroll
        for (int half = 0; half < 2; ++half) {
            if (half) __syncthreads();
#pragma unroll
            for (int mt = 0; mt < 2; ++mt)
#pragma unroll
                for (int q2 = 0; q2 < 8; ++q2) {
                    const int nt2 = half*8 + q2;
                    const int mrow = q2*16 + l15;
                    const int rbase = wm + mt*16 + l4*4;
                    ushort4 o;
                    o.x = f2h_u16(acc2[mt][nt2][0] - diagl[rbase+0]);
                    o.y = f2h_u16(acc2[mt][nt2][1] - diagl[rbase+1]);
                    o.z = f2h_u16(acc2[mt][nt2][2] - diagl[rbase+2]);
                    o.w = f2h_u16(acc2[mt][nt2][3] - diagl[rbase+3]);
                    *(ushort4*)&stage[mrow*LDS2 + rbase] = o;
                }
            __syncthreads();
#pragma unroll
            for (int i = 0; i < 8; ++i) {
                int lin = i*256 + tid;
                int mrow = lin >> 4, seg = lin & 15;
                *(uint4*)(ddT + (mb + half*128 + mrow)*LL + l0loc + seg*8) =
                    *(uint4*)&stage[mrow*LDS2 + seg*8];
            }
        }
    }
}

__global__ __launch_bounds__(256)
void kmax_final_kernel(const float* __restrict__ part, float* __restrict__ gmax)
{
    float mx = -3.0e38f;
    for (int i = threadIdx.x; i < 512; i += 256) mx = fmaxf(mx, part[i]);
#pragma unroll
    for (int off = 32; off > 0; off >>= 1) mx = fmaxf(mx, __shfl_xor(mx, off));
    __shared__ float wsm[4];
    if ((threadIdx.x & 63) == 0) wsm[threadIdx.x >> 6] = mx;
    __syncthreads();
    if (threadIdx.x == 0) gmax[0] = fmaxf(fmaxf(wsm[0], wsm[1]), fmaxf(wsm[2], wsm[3]));
}

// ---------------------------------------------------------------------------
// Per-chunk state (fully parallel, MFMA; verified round 7).
// ---------------------------------------------------------------------------
__global__ __launch_bounds__(256)
void chunk_state_mfma_kernel(const unsigned short* __restrict__ ddT,
                             const __hip_bfloat16* __restrict__ vT_b,
                             const float* __restrict__ gmax,
                             __hip_bfloat16* __restrict__ Sci_b,
                             float* __restrict__ skc,
                             __hip_bfloat16* __restrict__ kp_b)
{
    __shared__ __hip_bfloat16 kT[256*72];
    __shared__ __hip_bfloat16 vT[64*72];
    const int c = blockIdx.x, bh = blockIdx.y;
    const int tid = threadIdx.x, lane = tid & 63, w = tid >> 6;
    const int l15 = lane & 15, l4 = lane >> 4;
    const float gm = gmax[0];
    char* kbuf = (char*)&kT[0];
    char* vbuf = (char*)&vT[0];

    {
        const unsigned short* ksrc = ddT + ((size_t)bh*MM + tid)*LL + (size_t)c*64;
#pragma unroll
        for (int o = 0; o < 8; ++o) {
            uint4 r0 = *(const uint4*)(ksrc + o*8);
            const unsigned short* u0 = (const unsigned short*)&r0;
            unsigned short p0[8];
#pragma unroll
            for (int i = 0; i < 8; ++i)
                p0[i] = f2b_u16(K_RATIO * (__expf(h2f(u0[i]) - gm) + K_EPS));
            *(uint4*)(kbuf + KSWZ(tid, o*8)) = *(uint4*)&p0[0];
        }
        const int sr = tid >> 2, sq = tid & 3;
        const __hip_bfloat16* vsrc = vT_b + ((size_t)bh*DD + sr)*LL + (size_t)c*64 + sq*16;
        *(uint4*)(vbuf + sr*144 + sq*32)      = *(const uint4*)(vsrc);
        *(uint4*)(vbuf + sr*144 + sq*32 + 16) = *(const uint4*)(vsrc + 8);
    }
    __syncthreads();

    f32x4 accS[4][4];   // [dt][mt]
    f32x4 accK[4];
#pragma unroll
    for (int i = 0; i < 4; ++i) {
#pragma unroll
        for (int j = 0; j < 4; ++j) { f32x4 z = {0.f,0.f,0.f,0.f}; accS[i][j] = z; }
        f32x4 z = {0.f,0.f,0.f,0.f}; accK[i] = z;
    }
    short8 ones8;
    {
        const short ov = (short)0x3F80;   // bf16 1.0
#pragma unroll
        for (int i = 0; i < 8; ++i) ones8[i] = (l15 == 0) ? ov : (short)0;
    }

#pragma unroll
    for (int ks = 0; ks < 2; ++ks) {
        const int ko = ks*32 + l4*8;
        short8 bF[4], aF[4];
#pragma unroll
        for (int mt = 0; mt < 4; ++mt)
            bF[mt] = *(const short8*)(kbuf + KSWZ(w*64 + mt*16 + l15, ko));
#pragma unroll
        for (int dt = 0; dt < 4; ++dt)
            aF[dt] = *(const short8*)(vbuf + (dt*16 + l15)*144 + ko*2);
#pragma unroll
        for (int dt = 0; dt < 4; ++dt)
#pragma unroll
            for (int mt = 0; mt < 4; ++mt)
                accS[dt][mt] = __builtin_amdgcn_mfma_f32_16x16x32_bf16(aF[dt], bF[mt], accS[dt][mt], 0, 0, 0);
#pragma unroll
        for (int mt = 0; mt < 4; ++mt)
            accK[mt] = __builtin_amdgcn_mfma_f32_16x16x32_bf16(ones8, bF[mt], accK[mt], 0, 0, 0);
    }

    __hip_bfloat16* So = Sci_b + ((size_t)(bh*NCHUNK + c))*(MM*DD);
#pragma unroll
    for (int dt = 0; dt < 4; ++dt)
#pragma unroll
        for (int mt = 0; mt < 4; ++mt) {
            const int m = w*64 + mt*16 + l15;
#pragma unroll
            for (int j = 0; j < 4; ++j)
                So[(size_t)(dt*16 + l4*4 + j)*MM + m] = __float2bfloat16(accS[dt][mt][j]);
        }
    if (l4 == 0) {
#pragma unroll
        for (int mt = 0; mt < 4; ++mt)
            skc[((size_t)bh*NCHUNK + c)*MM + w*64 + mt*16 + l15] = accK[mt][0];
    }

    {
        const int t2 = w*16 + (lane >> 2);
        const int m0 = (lane & 3)*16;
        __hip_bfloat16* krow = kp_b + ((size_t)bh*LL + (size_t)c*64 + t2)*MM;
#pragma unroll
        for (int seg = 0; seg < 4; ++seg) {
            unsigned short vals[16];
#pragma unroll
            for (int i = 0; i < 16; ++i)
                vals[i] = *(const unsigned short*)(kbuf + KSWZ(seg*64 + m0 + i, t2));
            *(uint4*)(krow + seg*64 + m0)     = *(uint4*)&vals[0];
            *(uint4*)(krow + seg*64 + m0 + 8) = *(uint4*)&vals[8];
        }
    }
}

// ---------------------------------------------------------------------------
// Exclusive prefix over chunks, IN PLACE (verified round 7).
// ---------------------------------------------------------------------------
__global__ __launch_bounds__(256)
void chunk_prefix_kernel(__hip_bfloat16* __restrict__ S_b, float* __restrict__ skc)
{
    const int bh = blockIdx.y;
    const int e4 = blockIdx.x*256 + threadIdx.x;
    __hip_bfloat16* base = S_b + (size_t)bh*NCHUNK*(MM*DD) + (size_t)e4*4;
    float4 run = {0.f, 0.f, 0.f, 0.f};
#pragma unroll 4
    for (int c = 0; c < NCHUNK; ++c) {
        __hip_bfloat16* p = base + (size_t)c*(MM*DD);
        ushort4 t = *(ushort4*)p;
        ushort4 o;
        o.x = f2b_u16(run.x); o.y = f2b_u16(run.y);
        o.z = f2b_u16(run.z); o.w = f2b_u16(run.w);
        *(ushort4*)p = o;
        run.x += b2f_u16(t.x); run.y += b2f_u16(t.y);
        run.z += b2f_u16(t.z); run.w += b2f_u16(t.w);
    }
    if (blockIdx.x == 0) {
        float* kb = skc + (size_t)bh*NCHUNK*MM + threadIdx.x;
        float s2 = 0.f;
#pragma unroll 4
        for (int c = 0; c < NCHUNK; ++c) {
            float t = kb[(size_t)c*MM];
            kb[(size_t)c*MM] = s2;
            s2 += t;
        }
    }
}

// ---------------------------------------------------------------------------
// MFMA chunk_out (verified round 4, unchanged).
// ---------------------------------------------------------------------------
__global__ __launch_bounds__(256)
void chunk_out_kernel(const __hip_bfloat16* __restrict__ qp_b,
                      const __hip_bfloat16* __restrict__ kp_b,
                      const __hip_bfloat16* __restrict__ vT_b,
                      const __hip_bfloat16* __restrict__ ScT_b,
                      const float* __restrict__ skp,
                      __hip_bfloat16* __restrict__ attn)
{
    constexpr int LDQ = 72;
    constexpr int LDA = 72;
    __shared__ __hip_bfloat16 Qs[64*LDQ];
    __shared__ __hip_bfloat16 Ks[64*LDQ];
    __shared__ __hip_bfloat16 Ss[80*LDQ];
    __shared__ __hip_bfloat16 Al[64*LDA];
    __shared__ __hip_bfloat16 Vl[80*LDA];

    const int c = blockIdx.x, h = blockIdx.y, b = blockIdx.z;
    const size_t bh = (size_t)b*HH + h;
    const __hip_bfloat16* qpc = qp_b + (bh*LL + (size_t)c*TT) * MM;
    const __hip_bfloat16* kpc = kp_b + (bh*LL + (size_t)c*TT) * MM;
    const __hip_bfloat16* vTc = vT_b + bh*(size_t)(DD*LL) + (size_t)c*TT;
    const __hip_bfloat16* Scc = ScT_b + (bh*NCHUNK + (size_t)c) * (MM*DD);
    const float* skrow = skp + (bh*NCHUNK + (size_t)c) * MM;

    const int tid = threadIdx.x;
    const int lane = tid & 63;
    const int w = tid >> 6;
    const int l15 = lane & 15, l4 = lane >> 4;

    {
#pragma unroll
        for (int it = 0; it < 2; ++it) {
            int lin = it*256 + tid;
            int d = lin >> 3, c8 = (lin & 7)*8;
            *(uint4*)&Vl[d*LDA + c8] = *(const uint4*)(vTc + (size_t)d*LL + c8);
        }
        const __hip_bfloat16 one = __float2bfloat16(1.0f);
        const __hip_bfloat16 zero = __float2bfloat16(0.0f);
        for (int idx = tid; idx < 16*64; idx += 256) {
            int rr = idx >> 6, cc2 = idx & 63;
            Vl[(64+rr)*LDA + cc2] = (rr == 0) ? one : zero;
        }
        for (int idx = tid; idx < 15*64; idx += 256) {
            int rr = idx / 64, cc2 = idx % 64;
            Ss[(65+rr)*LDQ + cc2] = zero;
        }
    }

    f32x4 accA[4];
    f32x4 accO[5];
#pragma unroll
    for (int i = 0; i < 4; ++i) { f32x4 z = {0.f,0.f,0.f,0.f}; accA[i] = z; }
#pragma unroll
    for (int i = 0; i < 5; ++i) { f32x4 z = {0.f,0.f,0.f,0.f}; accO[i] = z; }

    for (int mq = 0; mq < MM; mq += 64) {
        __syncthreads();
#pragma unroll
        for (int it = 0; it < 2; ++it) {
            int lin = it*256 + tid;
            int r = lin >> 3, m8 = (lin & 7)*8;
            *(uint4*)&Qs[r*LDQ + m8] = *(const uint4*)(qpc + (size_t)r*MM + mq + m8);
            *(uint4*)&Ks[r*LDQ + m8] = *(const uint4*)(kpc + (size_t)r*MM + mq + m8);
            *(uint4*)&Ss[r*LDQ + m8] = *(const uint4*)(Scc + (size_t)r*MM + mq + m8);
        }
        if (tid < 64) Ss[64*LDQ + tid] = __float2bfloat16(skrow[mq + tid]);
        __syncthreads();
#pragma unroll
        for (int ks = 0; ks < 2; ++ks) {
            const int ko = ks*32 + l4*8;
            short8 aF = *(const short8*)&Qs[(w*16 + l15)*LDQ + ko];
#pragma unroll
            for (int nt = 0; nt < 4; ++nt) {
                short8 bF = *(const short8*)&Ks[(nt*16 + l15)*LDQ + ko];
                accA[nt] = __builtin_amdgcn_mfma_f32_16x16x32_bf16(aF, bF, accA[nt], 0, 0, 0);
            }
#pragma unroll
            for (int nt = 0; nt < 5; ++nt) {
                short8 sF = *(const short8*)&Ss[(nt*16 + l15)*LDQ + ko];
                accO[nt] = __builtin_amdgcn_mfma_f32_16x16x32_bf16(aF, sF, accO[nt], 0, 0, 0);
            }
        }
    }
    __syncthreads();
#pragma unroll
    for (int nt = 0; nt < 4; ++nt) {
        const int s = nt*16 + l15;
#pragma unroll
        for (int j = 0; j < 4; ++j) {
            const int t = w*16 + l4*4 + j;
            const float v = (s <= t) ? accA[nt][j] : 0.f;
            Al[t*LDA + s] = __float2bfloat16(v);
        }
    }
    __syncthreads();
#pragma unroll
    for (int ks = 0; ks < 2; ++ks) {
        const int ko = ks*32 + l4*8;
        short8 aF = *(const short8*)&Al[(w*16 + l15)*LDA + ko];
#pragma unroll
        for (int nt = 0; nt < 5; ++nt) {
            short8 vF = *(const short8*)&Vl[(nt*16 + l15)*LDA + ko];
            accO[nt] = __builtin_amdgcn_mfma_f32_16x16x32_bf16(aF, vF, accO[nt], 0, 0, 0);
        }
    }
    __hip_bfloat16* arow = attn + ((size_t)b*LL + (size_t)c*TT) * DIMM + h*DD;
#pragma unroll
    for (int j = 0; j < 4; ++j) {
        const float den = __shfl(accO[4][j], (lane & 48));
        const float inv = 1.0f / den;
        const int t = w*16 + l4*4 + j;
#pragma unroll
        for (int nt = 0; nt < 4; ++nt) {
            const int d = nt*16 + l15;
            arow[(size_t)t*DIMM + d] = __float2bfloat16(accO[nt][j] * inv);
        }
    }
}

// ---------------------------------------------------------------------------
// Final Wo GEMM, 128x64 tile (verified round 10), XCD-grouped tiles.
// ---------------------------------------------------------------------------
__global__ __launch_bounds__(256, 4)
void gemm_wo_kernel(const __hip_bfloat16* __restrict__ X, const __hip_bfloat16* __restrict__ W,
                    const float* __restrict__ bias, float* __restrict__ out)
{
    constexpr int LDT = 72;
    __shared__ __hip_bfloat16 As[128*LDT];
    __shared__ __hip_bfloat16 Bs[64*LDT];
    int ct, rt;
    xcd_remap(&ct, &rt);
    const int row0 = rt*128, col0 = ct*64;
    const int tid = threadIdx.x;
    const int lane = tid & 63;
    const int w = tid >> 6;
    const int wm = w * 32;
    const int l15 = lane & 15, l4 = lane >> 4;

    f32x4 acc[2][4];
#pragma unroll
    for (int mt = 0; mt < 2; ++mt)
#pragma unroll
        for (int nt = 0; nt < 4; ++nt) {
            f32x4 z = {0.f, 0.f, 0.f, 0.f};
            acc[mt][nt] = z;
        }

    for (int k0 = 0; k0 < DIMM; k0 += 64) {
#pragma unroll
        for (int i = 0; i < 4; ++i) {
            int lin = i*256 + tid;
            int r = lin >> 3, kc = (lin & 7)*8;
            *(uint4*)&As[r*LDT + kc] = *(const uint4*)(X + (size_t)(row0 + r)*DIMM + k0 + kc);
        }
#pragma unroll
        for (int i = 0; i < 2; ++i) {
            int lin = i*256 + tid;
            int r = lin >> 3, kc = (lin & 7)*8;
            *(uint4*)&Bs[r*LDT + kc] = *(const uint4*)(W + (size_t)(col0 + r)*DIMM + k0 + kc);
        }
        __syncthreads();
#pragma unroll
        for (int ks = 0; ks < 2; ++ks) {
            const int koff = ks*32 + l4*8;
            short8 aF[2], bF[4];
#pragma unroll
            for (int mt = 0; mt < 2; ++mt)
                aF[mt] = *(const short8*)&As[(wm + mt*16 + l15)*LDT + koff];
#pragma unroll
            for (int nt = 0; nt < 4; ++nt)
                bF[nt] = *(const short8*)&Bs[(nt*16 + l15)*LDT + koff];
#pragma unroll
            for (int mt = 0; mt < 2; ++mt)
#pragma unroll
                for (int nt = 0; nt < 4; ++nt)
                    acc[mt][nt] = __builtin_amdgcn_mfma_f32_16x16x32_bf16(aF[mt], bF[nt], acc[mt][nt], 0, 0, 0);
        }
        __syncthreads();
    }

#pragma unroll
    for (int mt = 0; mt < 2; ++mt) {
#pragma unroll
        for (int nt = 0; nt < 4; ++nt) {
            const int c = col0 + nt*16 + l15;
            const float bval = bias[c];
#pragma unroll
            for (int j = 0; j < 4; ++j) {
                const int r = row0 + wm + mt*16 + l4*4 + j;
                out[(size_t)r*DIMM + c] = acc[mt][nt][j] + bval;
            }
        }
    }
}

// ---------------------------------------------------------------------------
extern "C" void kernel_launch(void* const* d_in, const int* in_sizes, int n_in,
                              void* d_out, int out_size, void* d_ws, size_t ws_size,
                              hipStream_t stream)
{
    (void)in_sizes; (void)n_in; (void)out_size; (void)ws_size;
    const float* query = (const float*)d_in[0];
    const float* key   = (const float*)d_in[1];
    const float* value = (const float*)d_in[2];
    const float* Wq = (const float*)d_in[3];
    const float* bq = (const float*)d_in[4];
    const float* Wk = (const float*)d_in[5];
    const float* bk = (const float*)d_in[6];
    const float* Wv = (const float*)d_in[7];
    const float* bv = (const float*)d_in[8];
    const float* Wo = (const float*)d_in[9];
    const float* bo = (const float*)d_in[10];
    const float* proj = (const float*)d_in[11];

    float* ws = (float*)d_ws;
    unsigned short* ddT   = (unsigned short*)ws;                 // 16.7M f16  [bh][m][l]
    __hip_bfloat16* qp_b  = (__hip_bfloat16*)(ws +  8388608);
    __hip_bfloat16* kp_b  = (__hip_bfloat16*)(ws + 16777216);
    __hip_bfloat16* ScT_b = (__hip_bfloat16*)(ws + 25165824);
    __hip_bfloat16* vT_b  = (__hip_bfloat16*)(ws + 33554432);    // [bh][d][L] bf16
    __hip_bfloat16* attn_b= (__hip_bfloat16*)(ws + 35651584);    // [B,L,512] bf16
    __hip_bfloat16* qbi   = (__hip_bfloat16*)(ws + 37748736);
    __hip_bfloat16* kbi   = (__hip_bfloat16*)(ws + 39845888);
    __hip_bfloat16* vbi   = (__hip_bfloat16*)(ws + 41943040);
    __hip_bfloat16* Wqb   = (__hip_bfloat16*)(ws + 44040192);
    __hip_bfloat16* Wkb   = (__hip_bfloat16*)(ws + 44171264);
    __hip_bfloat16* Wvb   = (__hip_bfloat16*)(ws + 44302336);
    __hip_bfloat16* Wob   = (__hip_bfloat16*)(ws + 44433408);
    float* skc            = ws + 44564480;                       // 262,144 f32
    float* part           = ws + 44826624;                       // 512
    float* gmax           = ws + 44827136;                       // 1

    const dim3 blk(256);

    cast_all_kernel<<<2048, blk, 0, stream>>>(query, key, value, Wq, Wk, Wv, Wo,
                                              qbi, kbi, vbi, Wqb, Wkb, Wvb, Wob);

    // fused qkv projection + feature maps + V transpose
    qkv_feat_kernel<<<dim3(8,64,3), blk, 0, stream>>>(qbi, kbi, vbi,
                                                      Wqb, bq, Wkb, bk, Wvb, bv, proj,
                                                      qp_b, ddT, part, vT_b);

    kmax_final_kernel<<<1, blk, 0, stream>>>(part, gmax);

    chunk_state_mfma_kernel<<<dim3(NCHUNK,32), blk, 0, stream>>>(ddT, vT_b, gmax, ScT_b, skc, kp_b);
    chunk_prefix_kernel<<<dim3(16,32), blk, 0, stream>>>(ScT_b, skc);

    chunk_out_kernel<<<dim3(NCHUNK,HH,BB), blk, 0, stream>>>(qp_b, kp_b, vT_b, ScT_b, skc, attn_b);

    gemm_wo_kernel<<<dim3(8,64), blk, 0, stream>>>(attn_b, Wob, bo, (float*)d_out);
}

// Round 14
// 131.008 us; speedup vs baseline: 1.0429x; 1.0429x over previous
//
#include <hip/hip_runtime.h>
#include <hip/hip_bf16.h>
#include <math.h>

// Problem constants
#define BB 4
#define LL 2048
#define HH 8
#define DD 64          // head dim
#define MM 256         // nb_features
#define DIMM 512
#define TT 64          // chunk length
#define NCHUNK (LL/TT) // 32

constexpr float K_SCALE = 0.35355339059327379f; // 64^-0.25
constexpr float K_RATIO = 0.0625f;              // 256^-0.5
constexpr float K_EPS   = 1e-6f;

using short8 = __attribute__((ext_vector_type(8))) short;
using f32x4  = __attribute__((ext_vector_type(4))) float;
typedef _Float16 f16_t;

__device__ inline unsigned short f2b_u16(float x) {
    __hip_bfloat16 h = __float2bfloat16(x);
    return *reinterpret_cast<unsigned short*>(&h);
}
__device__ inline ushort4 f2b4(float4 v) {
    ushort4 o; o.x = f2b_u16(v.x); o.y = f2b_u16(v.y); o.z = f2b_u16(v.z); o.w = f2b_u16(v.w);
    return o;
}
__device__ inline unsigned short f2h_u16(float x) {
    f16_t h = (f16_t)x;
    return *reinterpret_cast<unsigned short*>(&h);
}
__device__ inline float h2f(unsigned short u) {
    f16_t h = *reinterpret_cast<f16_t*>(&u);
    return (float)h;
}
__device__ inline float b2f_u16(unsigned short u) {
    __hip_bfloat16 h = *reinterpret_cast<__hip_bfloat16*>(&u);
    return __bfloat162float(h);
}

// XOR-swizzled byte offset into the chunk_state kT tile ([m][t] bf16, row
// stride 72 elems = 144B).
#define KSWZ(m, te) ((((m)*144) + ((te)*2)) ^ ((((m)>>3) & 3) << 4))

// XOR-swizzled byte offset into the Pl proj tile ([m][k] bf16, linear 64-elem
// rows = 128B). Bits 4-6 XOR'd by (m>>1)&7.
#define PSWZ(m, ke) ((((m)*128) + ((ke)*2)) ^ ((((m)>>1) & 7) << 4))

// XCD-grouping remap for (8 ct, 64 rt) grids (verified rounds 8/12).
__device__ inline void xcd_remap(int* ct, int* rt) {
    const int fid = blockIdx.x + 8*blockIdx.y;   // 0..511
    const int xcd = fid & 7;
    *rt = xcd*8 + (fid >> 6);                    // 0..63
    *ct = (fid >> 3) & 7;                        // 0..7
}

// ---------------------------------------------------------------------------
// f32 -> bf16 casts: 4 weight matrices only (inputs now cast in-staging).
// ---------------------------------------------------------------------------
__global__ __launch_bounds__(256)
void cast_w_kernel(const float* __restrict__ w0, const float* __restrict__ w1,
                   const float* __restrict__ w2, const float* __restrict__ w3,
                   __hip_bfloat16* __restrict__ o0, __hip_bfloat16* __restrict__ o1,
                   __hip_bfloat16* __restrict__ o2, __hip_bfloat16* __restrict__ o3)
{
    const int NW = 1 << 16;    // float4 per weight
    const int total = 4*NW;
    for (int i = blockIdx.x*256 + threadIdx.x; i < total; i += gridDim.x*256) {
        const int t = i >> 16, j = i & (NW - 1);
        const float* src = (t == 0) ? w0 : (t == 1) ? w1 : (t == 2) ? w2 : w3;
        __hip_bfloat16* dst = (t == 0) ? o0 : (t == 1) ? o1 : (t == 2) ? o2 : o3;
        float4 x = reinterpret_cast<const float4*>(src)[j];
        reinterpret_cast<ushort4*>(dst)[j] = f2b4(x);
    }
}

// ---------------------------------------------------------------------------
// FUSED qkv projection + feature maps + V transpose (verified rounds 11-13),
// now reading f32 inputs directly (convert during A staging — identical
// rounding to the old pre-cast, bit-identical output).
// Grid (8 ct, 64 rt, 3 z), 256 threads = 4 waves.
// ---------------------------------------------------------------------------
__global__ __launch_bounds__(256, 3)
void qkv_feat_kernel(const float* __restrict__ Xq, const float* __restrict__ Xk,
                     const float* __restrict__ Xv,
                     const __hip_bfloat16* __restrict__ Wq, const float* __restrict__ bq,
                     const __hip_bfloat16* __restrict__ Wk, const float* __restrict__ bk,
                     const __hip_bfloat16* __restrict__ Wv, const float* __restrict__ bv,
                     const float* __restrict__ P,
                     __hip_bfloat16* __restrict__ qp_b, unsigned short* __restrict__ ddT,
                     float* __restrict__ part, __hip_bfloat16* __restrict__ vT_b)
{
    constexpr int LDT = 72;
    constexpr int LDS2 = 136;               // stage row pitch (272B = 17x16B)
    __shared__ __hip_bfloat16 smem[25600];  // 51.2KB: phase1 As|Bs; phase2 T|Pl; epi stage
    __shared__ float diagl[128];
    __shared__ float wmx[4];
    __hip_bfloat16* As = smem;              // 128*72
    __hip_bfloat16* Bs = smem + 9216;       // 64*72
    __hip_bfloat16* T  = smem;              // aliases As after barrier
    char* pbuf = (char*)(smem + 9216);      // Pl 256x64 PSWZ (32768B)
    unsigned short* stage = (unsigned short*)smem;  // epilogue stage 128*136*2

    const int z = blockIdx.z;
    const float* X = (z == 0) ? Xq : (z == 1) ? Xk : Xv;
    const __hip_bfloat16* W = (z == 0) ? Wq : (z == 1) ? Wk : Wv;
    const float* bias = (z == 0) ? bq : (z == 1) ? bk : bv;
    const float postscale = (z == 2) ? 1.0f : K_SCALE;

    int ct, rt;
    xcd_remap(&ct, &rt);
    const int row0 = rt*128, col0 = ct*64;
    const int tid = threadIdx.x;
    const int lane = tid & 63;
    const int w = tid >> 6;
    const int wm = w * 32;
    const int l15 = lane & 15, l4 = lane >> 4;

    // ---- phase 1: projection (A staged from f32 with convert) ----
    f32x4 acc[2][4];
#pragma unroll
    for (int mt = 0; mt < 2; ++mt)
#pragma unroll
        for (int nt = 0; nt < 4; ++nt) {
            f32x4 zf = {0.f, 0.f, 0.f, 0.f};
            acc[mt][nt] = zf;
        }

    for (int k0 = 0; k0 < DIMM; k0 += 64) {
#pragma unroll
        for (int i = 0; i < 8; ++i) {
            int lin = i*256 + tid;              // 0..2047
            int r = lin >> 4, kc = (lin & 15)*4;
            float4 a = *(const float4*)(X + (size_t)(row0 + r)*DIMM + k0 + kc);
            *(ushort4*)&As[r*LDT + kc] = f2b4(a);
        }
#pragma unroll
        for (int i = 0; i < 2; ++i) {
            int lin = i*256 + tid;
            int r = lin >> 3, kc = (lin & 7)*8;
            *(uint4*)&Bs[r*LDT + kc] = *(const uint4*)(W + (size_t)(col0 + r)*DIMM + k0 + kc);
        }
        __syncthreads();
#pragma unroll
        for (int ks = 0; ks < 2; ++ks) {
            const int koff = ks*32 + l4*8;
            short8 aF[2], bF[4];
#pragma unroll
            for (int mt = 0; mt < 2; ++mt)
                aF[mt] = *(const short8*)&As[(wm + mt*16 + l15)*LDT + koff];
#pragma unroll
            for (int nt = 0; nt < 4; ++nt)
                bF[nt] = *(const short8*)&Bs[(nt*16 + l15)*LDT + koff];
#pragma unroll
            for (int mt = 0; mt < 2; ++mt)
#pragma unroll
                for (int nt = 0; nt < 4; ++nt)
                    acc[mt][nt] = __builtin_amdgcn_mfma_f32_16x16x32_bf16(aF[mt], bF[nt], acc[mt][nt], 0, 0, 0);
        }
        __syncthreads();
    }

    // ---- phase 2: tile -> T (bias+scale, bf16) ----
#pragma unroll
    for (int mt = 0; mt < 2; ++mt)
#pragma unroll
        for (int nt = 0; nt < 4; ++nt) {
            const float bval = bias[col0 + nt*16 + l15];
#pragma unroll
            for (int j = 0; j < 4; ++j) {
                const int r = wm + mt*16 + l4*4 + j;
                T[r*LDT + nt*16 + l15] = __float2bfloat16((acc[mt][nt][j] + bval) * postscale);
            }
        }
    if (z != 2) {
#pragma unroll
        for (int i = 0; i < 16; ++i) {
            int lin = i*256 + tid;
            int r = lin >> 4, kc = (lin & 15)*4;
            float4 v = *(const float4*)(P + (size_t)r*64 + kc);
            ushort4 o = f2b4(v);
            *(ushort4*)(pbuf + PSWZ(r, kc)) = o;
        }
    }
    __syncthreads();

    if (z == 2) {
        const int d = tid >> 2, q = tid & 3;
        const int b = row0 >> 11, l0loc = row0 & 2047;
        __hip_bfloat16* dst = vT_b + (((size_t)b*HH + ct)*DD + d)*LL + l0loc + q*32;
#pragma unroll
        for (int g = 0; g < 8; ++g) {
            ushort4 o;
            o.x = *(unsigned short*)&T[(q*32 + g*4 + 0)*LDT + d];
            o.y = *(unsigned short*)&T[(q*32 + g*4 + 1)*LDT + d];
            o.z = *(unsigned short*)&T[(q*32 + g*4 + 2)*LDT + d];
            o.w = *(unsigned short*)&T[(q*32 + g*4 + 3)*LDT + d];
            *(ushort4*)(dst + g*4) = o;
        }
        return;
    }

    // diag partials (reads T)
    {
        const int r = tid >> 1, half = tid & 1;
        float s = 0.f;
#pragma unroll
        for (int i = 0; i < 32; ++i) {
            float x = __bfloat162float(T[r*LDT + half*32 + i]);
            s += x*x;
        }
        s += __shfl_xor(s, 1);
        if (half == 0) diagl[r] = 0.5f * s;
    }

    // feature MFMA: dd[128 l x 256 m], K=64. acc2[mt 2][nt2 16].
    f32x4 acc2[2][16];
#pragma unroll
    for (int mt = 0; mt < 2; ++mt)
#pragma unroll
        for (int nt2 = 0; nt2 < 16; ++nt2) {
            f32x4 zf = {0.f,0.f,0.f,0.f};
            acc2[mt][nt2] = zf;
        }
#pragma unroll
    for (int ks = 0; ks < 2; ++ks) {
        const int ko = ks*32 + l4*8;
        short8 aF[2];
#pragma unroll
        for (int mt = 0; mt < 2; ++mt)
            aF[mt] = *(const short8*)&T[(wm + mt*16 + l15)*LDT + ko];
#pragma unroll
        for (int nt2 = 0; nt2 < 16; ++nt2) {
            short8 bF = *(const short8*)(pbuf + PSWZ(nt2*16 + l15, ko));
#pragma unroll
            for (int mt = 0; mt < 2; ++mt)
                acc2[mt][nt2] = __builtin_amdgcn_mfma_f32_16x16x32_bf16(aF[mt], bF, acc2[mt][nt2], 0, 0, 0);
        }
    }

    if (z == 1) {
        float mx = -3.0e38f;
#pragma unroll
        for (int mt = 0; mt < 2; ++mt)
#pragma unroll
            for (int nt2 = 0; nt2 < 16; ++nt2)
#pragma unroll
                for (int j = 0; j < 4; ++j)
                    mx = fmaxf(mx, acc2[mt][nt2][j]);
#pragma unroll
        for (int off = 32; off > 0; off >>= 1) mx = fmaxf(mx, __shfl_xor(mx, off));
        if (lane == 0) wmx[w] = mx;
    }
    __syncthreads();   // diagl (and wmx) ready; T/Pl now dead -> stage reuse OK

    const int b = row0 >> 11, l0loc = row0 & 2047;

    if (z == 0) {
        float ccv[2][4];
#pragma unroll
        for (int mt = 0; mt < 2; ++mt)
#pragma unroll
            for (int j = 0; j < 4; ++j) {
                float m = acc2[mt][0][j];
#pragma unroll
                for (int nt2 = 1; nt2 < 16; ++nt2) m = fmaxf(m, acc2[mt][nt2][j]);
                m = fmaxf(m, __shfl_xor(m, 1));
                m = fmaxf(m, __shfl_xor(m, 2));
                m = fmaxf(m, __shfl_xor(m, 4));
                m = fmaxf(m, __shfl_xor(m, 8));
                ccv[mt][j] = diagl[wm + mt*16 + l4*4 + j] + m;
            }
        const size_t gb = ((size_t)b*HH + ct)*LL + l0loc;
#pragma unroll
        for (int half = 0; half < 2; ++half) {
            if (half) __syncthreads();
#pragma unroll
            for (int mt = 0; mt < 2; ++mt)
#pragma unroll
                for (int j = 0; j < 4; ++j) {
                    const int r = wm + mt*16 + l4*4 + j;
                    const float cc = ccv[mt][j];
#pragma unroll
                    for (int q2 = 0; q2 < 8; ++q2) {
                        const int nt2 = half*8 + q2;
                        stage[r*LDS2 + q2*16 + l15] =
                            f2b_u16(K_RATIO * (__expf(acc2[mt][nt2][j] - cc) + K_EPS));
                    }
                }
            __syncthreads();
#pragma unroll
            for (int i = 0; i < 8; ++i) {
                int lin = i*256 + tid;
                int r = lin >> 4, seg = lin & 15;
                *(uint4*)(qp_b + (gb + r)*MM + half*128 + seg*8) =
                    *(uint4*)&stage[r*LDS2 + seg*8];
            }
        }
    } else {
        if (tid == 0)
            part[rt*8 + ct] = fmaxf(fmaxf(wmx[0], wmx[1]), fmaxf(wmx[2], wmx[3]));
        const size_t mb = ((size_t)b*HH + ct)*MM;
#pragma unroll
        for (int half = 0; half < 2; ++half) {
            if (half) __syncthreads();
#pragma unroll
            for (int mt = 0; mt < 2; ++mt)
#pragma unroll
                for (int q2 = 0; q2 < 8; ++q2) {
                    const int nt2 = half*8 + q2;
                    const int mrow = q2*16 + l15;
                    const int rbase = wm + mt*16 + l4*4;
                    ushort4 o;
                    o.x = f2h_u16(acc2[mt][nt2][0] - diagl[rbase+0]);
                    o.y = f2h_u16(acc2[mt][nt2][1] - diagl[rbase+1]);
                    o.z = f2h_u16(acc2[mt][nt2][2] - diagl[rbase+2]);
                    o.w = f2h_u16(acc2[mt][nt2][3] - diagl[rbase+3]);
                    *(ushort4*)&stage[mrow*LDS2 + rbase] = o;
                }
            __syncthreads();
#pragma unroll
            for (int i = 0; i < 8; ++i) {
                int lin = i*256 + tid;
                int mrow = lin >> 4, seg = lin & 15;
                *(uint4*)(ddT + (mb + half*128 + mrow)*LL + l0loc + seg*8) =
                    *(uint4*)&stage[mrow*LDS2 + seg*8];
            }
        }
    }
}

__global__ __launch_bounds__(256)
void kmax_final_kernel(const float* __restrict__ part, float* __restrict__ gmax)
{
    float mx = -3.0e38f;
    for (int i = threadIdx.x; i < 512; i += 256) mx = fmaxf(mx, part[i]);
#pragma unroll
    for (int off = 32; off > 0; off >>= 1) mx = fmaxf(mx, __shfl_xor(mx, off));
    __shared__ float wsm[4];
    if ((threadIdx.x & 63) == 0) wsm[threadIdx.x >> 6] = mx;
    __syncthreads();
    if (threadIdx.x == 0) gmax[0] = fmaxf(fmaxf(wsm[0], wsm[1]), fmaxf(wsm[2], wsm[3]));
}

// ---------------------------------------------------------------------------
// Per-chunk state (fully parallel, MFMA; verified round 7).
// ---------------------------------------------------------------------------
__global__ __launch_bounds__(256)
void chunk_state_mfma_kernel(const unsigned short* __restrict__ ddT,
                             const __hip_bfloat16* __restrict__ vT_b,
                             const float* __restrict__ gmax,
                             __hip_bfloat16* __restrict__ Sci_b,
                             float* __restrict__ skc,
                             __hip_bfloat16* __restrict__ kp_b)
{
    __shared__ __hip_bfloat16 kT[256*72];
    __shared__ __hip_bfloat16 vT[64*72];
    const int c = blockIdx.x, bh = blockIdx.y;
    const int tid = threadIdx.x, lane = tid & 63, w = tid >> 6;
    const int l15 = lane & 15, l4 = lane >> 4;
    const float gm = gmax[0];
    char* kbuf = (char*)&kT[0];
    char* vbuf = (char*)&vT[0];

    {
        const unsigned short* ksrc = ddT + ((size_t)bh*MM + tid)*LL + (size_t)c*64;
#pragma unroll
        for (int o = 0; o < 8; ++o) {
            uint4 r0 = *(const uint4*)(ksrc + o*8);
            const unsigned short* u0 = (const unsigned short*)&r0;
            unsigned short p0[8];
#pragma unroll
            for (int i = 0; i < 8; ++i)
                p0[i] = f2b_u16(K_RATIO * (__expf(h2f(u0[i]) - gm) + K_EPS));
            *(uint4*)(kbuf + KSWZ(tid, o*8)) = *(uint4*)&p0[0];
        }
        const int sr = tid >> 2, sq = tid & 3;
        const __hip_bfloat16* vsrc = vT_b + ((size_t)bh*DD + sr)*LL + (size_t)c*64 + sq*16;
        *(uint4*)(vbuf + sr*144 + sq*32)      = *(const uint4*)(vsrc);
        *(uint4*)(vbuf + sr*144 + sq*32 + 16) = *(const uint4*)(vsrc + 8);
    }
    __syncthreads();

    f32x4 accS[4][4];   // [dt][mt]
    f32x4 accK[4];
#pragma unroll
    for (int i = 0; i < 4; ++i) {
#pragma unroll
        for (int j = 0; j < 4; ++j) { f32x4 z = {0.f,0.f,0.f,0.f}; accS[i][j] = z; }
        f32x4 z = {0.f,0.f,0.f,0.f}; accK[i] = z;
    }
    short8 ones8;
    {
        const short ov = (short)0x3F80;   // bf16 1.0
#pragma unroll
        for (int i = 0; i < 8; ++i) ones8[i] = (l15 == 0) ? ov : (short)0;
    }

#pragma unroll
    for (int ks = 0; ks < 2; ++ks) {
        const int ko = ks*32 + l4*8;
        short8 bF[4], aF[4];
#pragma unroll
        for (int mt = 0; mt < 4; ++mt)
            bF[mt] = *(const short8*)(kbuf + KSWZ(w*64 + mt*16 + l15, ko));
#pragma unroll
        for (int dt = 0; dt < 4; ++dt)
            aF[dt] = *(const short8*)(vbuf + (dt*16 + l15)*144 + ko*2);
#pragma unroll
        for (int dt = 0; dt < 4; ++dt)
#pragma unroll
            for (int mt = 0; mt < 4; ++mt)
                accS[dt][mt] = __builtin_amdgcn_mfma_f32_16x16x32_bf16(aF[dt], bF[mt], accS[dt][mt], 0, 0, 0);
#pragma unroll
        for (int mt = 0; mt < 4; ++mt)
            accK[mt] = __builtin_amdgcn_mfma_f32_16x16x32_bf16(ones8, bF[mt], accK[mt], 0, 0, 0);
    }

    __hip_bfloat16* So = Sci_b + ((size_t)(bh*NCHUNK + c))*(MM*DD);
#pragma unroll
    for (int dt = 0; dt < 4; ++dt)
#pragma unroll
        for (int mt = 0; mt < 4; ++mt) {
            const int m = w*64 + mt*16 + l15;
#pragma unroll
            for (int j = 0; j < 4; ++j)
                So[(size_t)(dt*16 + l4*4 + j)*MM + m] = __float2bfloat16(accS[dt][mt][j]);
        }
    if (l4 == 0) {
#pragma unroll
        for (int mt = 0; mt < 4; ++mt)
            skc[((size_t)bh*NCHUNK + c)*MM + w*64 + mt*16 + l15] = accK[mt][0];
    }

    {
        const int t2 = w*16 + (lane >> 2);
        const int m0 = (lane & 3)*16;
        __hip_bfloat16* krow = kp_b + ((size_t)bh*LL + (size_t)c*64 + t2)*MM;
#pragma unroll
        for (int seg = 0; seg < 4; ++seg) {
            unsigned short vals[16];
#pragma unroll
            for (int i = 0; i < 16; ++i)
                vals[i] = *(const unsigned short*)(kbuf + KSWZ(seg*64 + m0 + i, t2));
            *(uint4*)(krow + seg*64 + m0)     = *(uint4*)&vals[0];
            *(uint4*)(krow + seg*64 + m0 + 8) = *(uint4*)&vals[8];
        }
    }
}

// ---------------------------------------------------------------------------
// Exclusive prefix over chunks, IN PLACE (verified round 7).
// ---------------------------------------------------------------------------
__global__ __launch_bounds__(256)
void chunk_prefix_kernel(__hip_bfloat16* __restrict__ S_b, float* __restrict__ skc)
{
    const int bh = blockIdx.y;
    const int e4 = blockIdx.x*256 + threadIdx.x;
    __hip_bfloat16* base = S_b + (size_t)bh*NCHUNK*(MM*DD) + (size_t)e4*4;
    float4 run = {0.f, 0.f, 0.f, 0.f};
#pragma unroll 4
    for (int c = 0; c < NCHUNK; ++c) {
        __hip_bfloat16* p = base + (size_t)c*(MM*DD);
        ushort4 t = *(ushort4*)p;
        ushort4 o;
        o.x = f2b_u16(run.x); o.y = f2b_u16(run.y);
        o.z = f2b_u16(run.z); o.w = f2b_u16(run.w);
        *(ushort4*)p = o;
        run.x += b2f_u16(t.x); run.y += b2f_u16(t.y);
        run.z += b2f_u16(t.z); run.w += b2f_u16(t.w);
    }
    if (blockIdx.x == 0) {
        float* kb = skc + (size_t)bh*NCHUNK*MM + threadIdx.x;
        float s2 = 0.f;
#pragma unroll 4
        for (int c = 0; c < NCHUNK; ++c) {
            float t = kb[(size_t)c*MM];
            kb[(size_t)c*MM] = s2;
            s2 += t;
        }
    }
}

// ---------------------------------------------------------------------------
// MFMA chunk_out (verified round 4, unchanged).
// ---------------------------------------------------------------------------
__global__ __launch_bounds__(256)
void chunk_out_kernel(const __hip_bfloat16* __restrict__ qp_b,
                      const __hip_bfloat16* __restrict__ kp_b,
                      const __hip_bfloat16* __restrict__ vT_b,
                      const __hip_bfloat16* __restrict__ ScT_b,
                      const float* __restrict__ skp,
                      __hip_bfloat16* __restrict__ attn)
{
    constexpr int LDQ = 72;
    constexpr int LDA = 72;
    __shared__ __hip_bfloat16 Qs[64*LDQ];
    __shared__ __hip_bfloat16 Ks[64*LDQ];
    __shared__ __hip_bfloat16 Ss[80*LDQ];
    __shared__ __hip_bfloat16 Al[64*LDA];
    __shared__ __hip_bfloat16 Vl[80*LDA];

    const int c = blockIdx.x, h = blockIdx.y, b = blockIdx.z;
    const size_t bh = (size_t)b*HH + h;
    const __hip_bfloat16* qpc = qp_b + (bh*LL + (size_t)c*TT) * MM;
    const __hip_bfloat16* kpc = kp_b + (bh*LL + (size_t)c*TT) * MM;
    const __hip_bfloat16* vTc = vT_b + bh*(size_t)(DD*LL) + (size_t)c*TT;
    const __hip_bfloat16* Scc = ScT_b + (bh*NCHUNK + (size_t)c) * (MM*DD);
    const float* skrow = skp + (bh*NCHUNK + (size_t)c) * MM;

    const int tid = threadIdx.x;
    const int lane = tid & 63;
    const int w = tid >> 6;
    const int l15 = lane & 15, l4 = lane >> 4;

    {
#pragma unroll
        for (int it = 0; it < 2; ++it) {
            int lin = it*256 + tid;
            int d = lin >> 3, c8 = (lin & 7)*8;
            *(uint4*)&Vl[d*LDA + c8] = *(const uint4*)(vTc + (size_t)d*LL + c8);
        }
        const __hip_bfloat16 one = __float2bfloat16(1.0f);
        const __hip_bfloat16 zero = __float2bfloat16(0.0f);
        for (int idx = tid; idx < 16*64; idx += 256) {
            int rr = idx >> 6, cc2 = idx & 63;
            Vl[(64+rr)*LDA + cc2] = (rr == 0) ? one : zero;
        }
        for (int idx = tid; idx < 15*64; idx += 256) {
            int rr = idx / 64, cc2 = idx % 64;
            Ss[(65+rr)*LDQ + cc2] = zero;
        }
    }

    f32x4 accA[4];
    f32x4 accO[5];
#pragma unroll
    for (int i = 0; i < 4; ++i) { f32x4 z = {0.f,0.f,0.f,0.f}; accA[i] = z; }
#pragma unroll
    for (int i = 0; i < 5; ++i) { f32x4 z = {0.f,0.f,0.f,0.f}; accO[i] = z; }

    for (int mq = 0; mq < MM; mq += 64) {
        __syncthreads();
#pragma unroll
        for (int it = 0; it < 2; ++it) {
            int lin = it*256 + tid;
            int r = lin >> 3, m8 = (lin & 7)*8;
            *(uint4*)&Qs[r*LDQ + m8] = *(const uint4*)(qpc + (size_t)r*MM + mq + m8);
            *(uint4*)&Ks[r*LDQ + m8] = *(const uint4*)(kpc + (size_t)r*MM + mq + m8);
            *(uint4*)&Ss[r*LDQ + m8] = *(const uint4*)(Scc + (size_t)r*MM + mq + m8);
        }
        if (tid < 64) Ss[64*LDQ + tid] = __float2bfloat16(skrow[mq + tid]);
        __syncthreads();
#pragma unroll
        for (int ks = 0; ks < 2; ++ks) {
            const int ko = ks*32 + l4*8;
            short8 aF = *(const short8*)&Qs[(w*16 + l15)*LDQ + ko];
#pragma unroll
            for (int nt = 0; nt < 4; ++nt) {
                short8 bF = *(const short8*)&Ks[(nt*16 + l15)*LDQ + ko];
                accA[nt] = __builtin_amdgcn_mfma_f32_16x16x32_bf16(aF, bF, accA[nt], 0, 0, 0);
            }
#pragma unroll
            for (int nt = 0; nt < 5; ++nt) {
                short8 sF = *(const short8*)&Ss[(nt*16 + l15)*LDQ + ko];
                accO[nt] = __builtin_amdgcn_mfma_f32_16x16x32_bf16(aF, sF, accO[nt], 0, 0, 0);
            }
        }
    }
    __syncthreads();
#pragma unroll
    for (int nt = 0; nt < 4; ++nt) {
        const int s = nt*16 + l15;
#pragma unroll
        for (int j = 0; j < 4; ++j) {
            const int t = w*16 + l4*4 + j;
            const float v = (s <= t) ? accA[nt][j] : 0.f;
            Al[t*LDA + s] = __float2bfloat16(v);
        }
    }
    __syncthreads();
#pragma unroll
    for (int ks = 0; ks < 2; ++ks) {
        const int ko = ks*32 + l4*8;
        short8 aF = *(const short8*)&Al[(w*16 + l15)*LDA + ko];
#pragma unroll
        for (int nt = 0; nt < 5; ++nt) {
            short8 vF = *(const short8*)&Vl[(nt*16 + l15)*LDA + ko];
            accO[nt] = __builtin_amdgcn_mfma_f32_16x16x32_bf16(aF, vF, accO[nt], 0, 0, 0);
        }
    }
    __hip_bfloat16* arow = attn + ((size_t)b*LL + (size_t)c*TT) * DIMM + h*DD;
#pragma unroll
    for (int j = 0; j < 4; ++j) {
        const float den = __shfl(accO[4][j], (lane & 48));
        const float inv = 1.0f / den;
        const int t = w*16 + l4*4 + j;
#pragma unroll
        for (int nt = 0; nt < 4; ++nt) {
            const int d = nt*16 + l15;
            arow[(size_t)t*DIMM + d] = __float2bfloat16(accO[nt][j] * inv);
        }
    }
}

// ---------------------------------------------------------------------------
// Final Wo GEMM, 128x64 tile (verified round 10), XCD-grouped tiles.
// ---------------------------------------------------------------------------
__global__ __launch_bounds__(256, 4)
void gemm_wo_kernel(const __hip_bfloat16* __restrict__ X, const __hip_bfloat16* __restrict__ W,
                    const float* __restrict__ bias, float* __restrict__ out)
{
    constexpr int LDT = 72;
    __shared__ __hip_bfloat16 As[128*LDT];
    __shared__ __hip_bfloat16 Bs[64*LDT];
    int ct, rt;
    xcd_remap(&ct, &rt);
    const int row0 = rt*128, col0 = ct*64;
    const int tid = threadIdx.x;
    const int lane = tid & 63;
    const int w = tid >> 6;
    const int wm = w * 32;
    const int l15 = lane & 15, l4 = lane >> 4;

    f32x4 acc[2][4];
#pragma unroll
    for (int mt = 0; mt < 2; ++mt)
#pragma unroll
        for (int nt = 0; nt < 4; ++nt) {
            f32x4 z = {0.f, 0.f, 0.f, 0.f};
            acc[mt][nt] = z;
        }

    for (int k0 = 0; k0 < DIMM; k0 += 64) {
#pragma unroll
        for (int i = 0; i < 4; ++i) {
            int lin = i*256 + tid;
            int r = lin >> 3, kc = (lin & 7)*8;
            *(uint4*)&As[r*LDT + kc] = *(const uint4*)(X + (size_t)(row0 + r)*DIMM + k0 + kc);
        }
#pragma unroll
        for (int i = 0; i < 2; ++i) {
            int lin = i*256 + tid;
            int r = lin >> 3, kc = (lin & 7)*8;
            *(uint4*)&Bs[r*LDT + kc] = *(const uint4*)(W + (size_t)(col0 + r)*DIMM + k0 + kc);
        }
        __syncthreads();
#pragma unroll
        for (int ks = 0; ks < 2; ++ks) {
            const int koff = ks*32 + l4*8;
            short8 aF[2], bF[4];
#pragma unroll
            for (int mt = 0; mt < 2; ++mt)
                aF[mt] = *(const short8*)&As[(wm + mt*16 + l15)*LDT + koff];
#pragma unroll
            for (int nt = 0; nt < 4; ++nt)
                bF[nt] = *(const short8*)&Bs[(nt*16 + l15)*LDT + koff];
#pragma unroll
            for (int mt = 0; mt < 2; ++mt)
#pragma unroll
                for (int nt = 0; nt < 4; ++nt)
                    acc[mt][nt] = __builtin_amdgcn_mfma_f32_16x16x32_bf16(aF[mt], bF[nt], acc[mt][nt], 0, 0, 0);
        }
        __syncthreads();
    }

#pragma unroll
    for (int mt = 0; mt < 2; ++mt) {
#pragma unroll
        for (int nt = 0; nt < 4; ++nt) {
            const int c = col0 + nt*16 + l15;
            const float bval = bias[c];
#pragma unroll
            for (int j = 0; j < 4; ++j) {
                const int r = row0 + wm + mt*16 + l4*4 + j;
                out[(size_t)r*DIMM + c] = acc[mt][nt][j] + bval;
            }
        }
    }
}

// ---------------------------------------------------------------------------
extern "C" void kernel_launch(void* const* d_in, const int* in_sizes, int n_in,
                              void* d_out, int out_size, void* d_ws, size_t ws_size,
                              hipStream_t stream)
{
    (void)in_sizes; (void)n_in; (void)out_size; (void)ws_size;
    const float* query = (const float*)d_in[0];
    const float* key   = (const float*)d_in[1];
    const float* value = (const float*)d_in[2];
    const float* Wq = (const float*)d_in[3];
    const float* bq = (const float*)d_in[4];
    const float* Wk = (const float*)d_in[5];
    const float* bk = (const float*)d_in[6];
    const float* Wv = (const float*)d_in[7];
    const float* bv = (const float*)d_in[8];
    const float* Wo = (const float*)d_in[9];
    const float* bo = (const float*)d_in[10];
    const float* proj = (const float*)d_in[11];

    float* ws = (float*)d_ws;
    unsigned short* ddT   = (unsigned short*)ws;                 // 16.7M f16  [bh][m][l]
    __hip_bfloat16* qp_b  = (__hip_bfloat16*)(ws +  8388608);
    __hip_bfloat16* kp_b  = (__hip_bfloat16*)(ws + 16777216);
    __hip_bfloat16* ScT_b = (__hip_bfloat16*)(ws + 25165824);
    __hip_bfloat16* vT_b  = (__hip_bfloat16*)(ws + 33554432);    // [bh][d][L] bf16
    __hip_bfloat16* attn_b= (__hip_bfloat16*)(ws + 35651584);    // [B,L,512] bf16
    __hip_bfloat16* Wqb   = (__hip_bfloat16*)(ws + 37748736);
    __hip_bfloat16* Wkb   = (__hip_bfloat16*)(ws + 37879808);
    __hip_bfloat16* Wvb   = (__hip_bfloat16*)(ws + 38010880);
    __hip_bfloat16* Wob   = (__hip_bfloat16*)(ws + 38141952);
    float* skc            = ws + 38273024;                       // 262,144 f32
    float* part           = ws + 38535168;                       // 512
    float* gmax           = ws + 38535680;                       // 1

    const dim3 blk(256);

    cast_w_kernel<<<256, blk, 0, stream>>>(Wq, Wk, Wv, Wo, Wqb, Wkb, Wvb, Wob);

    // fused qkv projection + feature maps + V transpose (f32 inputs direct)
    qkv_feat_kernel<<<dim3(8,64,3), blk, 0, stream>>>(query, key, value,
                                                      Wqb, bq, Wkb, bk, Wvb, bv, proj,
                                                      qp_b, ddT, part, vT_b);

    kmax_final_kernel<<<1, blk, 0, stream>>>(part, gmax);

    chunk_state_mfma_kernel<<<dim3(NCHUNK,32), blk, 0, stream>>>(ddT, vT_b, gmax, ScT_b, skc, kp_b);
    chunk_prefix_kernel<<<dim3(16,32), blk, 0, stream>>>(ScT_b, skc);

    chunk_out_kernel<<<dim3(NCHUNK,HH,BB), blk, 0, stream>>>(qp_b, kp_b, vT_b, ScT_b, skc, attn_b);

    gemm_wo_kernel<<<dim3(8,64), blk, 0, stream>>>(attn_b, Wob, bo, (float*)d_out);
}